// Round 1
// 362.981 us; speedup vs baseline: 1.0320x; 1.0320x over previous
//
#include <hip/hip_runtime.h>
#include <hip/hip_fp16.h>
#include <math.h>

// Decomposition:
//   t1 = lrelu(feat@W1+b1) (in-wave inside k_A)
//   A = t1 @ Wc + bc  (Wc=W2@Wnm_top: h only feeds A)
//   a_s = A@m; bd[v] = feat[v]@qb (fused into k_A)
//   w_e = exp(lrelu(a_s[src] + c1*bit + bd[dst] + c0, 0.2))  (fp32; no max)
//   neigh[v] = (sum w_e*A[src] + (sum w_e*bit)*wbit)/sum_w + B[v] + b_nm
//   out = mlp_out(relu(neigh))
// R1: same-address atomicAdd serializes -> block reduce.
// R6: fp16 A gather. R13: MFMA for dense matvecs.
// R7/R8/R14/R16: single-pass CSR fill = 1 random dirty 64B line/edge (~97us,
//     WRITE_SIZE == E*64B exactly).
// R17-R19: mid-tier is dispatch-count bound. k_t1/bd fused into k_A; scan_b
//     folded into scan_c.
// R20: k_hp = hist+prep; k_Ac = scan_c + k_A.
// R21: replace random-scatter k_fill with 2-pass binned sort:
//     k_p1: LDS histogram over 782 dst-buckets (128 nodes), reserve runs via
//           1 atomic per (block,bucket), write ~168B contiguous runs -> L2
//           merges full lines within one XCD. bcur init folded into k_Ac scan.
//     k_p2: 1 block/bucket, stream in, LDS scatter to per-node order (no
//           global atomics), stream out coalesced. tmp aliases h_node.

typedef _Float16 h2f __attribute__((ext_vector_type(2)));
typedef _Float16 h8  __attribute__((ext_vector_type(8)));
typedef float    f4  __attribute__((ext_vector_type(4)));

#define GSZ_SHIFT 7
#define GSZ 128
#define NBMAX 800
#define EPB 8192
#define P2CAP 2816

static __device__ __forceinline__ float lrelu(float x, float s) {
    return x >= 0.f ? x : s * x;
}

// ---------- k_hp: blk0 -> sc; blk1..33 -> Wc,bc; blk34.. -> dst histogram ----------
// sc[0]=c1=wbit@m  sc[1]=c0=b_nm@m  sc[2+k]=qb[k]=Wnm[129+k]@m
__global__ void __launch_bounds__(256) k_hp(const float* __restrict__ W2,
                                            const float* __restrict__ b2,
                                            const float* __restrict__ Wnm,
                                            const float* __restrict__ b_nm,
                                            const float* __restrict__ attn,
                                            __half* __restrict__ Wc,
                                            float* __restrict__ bc,
                                            float* __restrict__ sc,
                                            const int* __restrict__ dst,
                                            int* __restrict__ counts, int E) {
    int t = threadIdx.x;
    if (blockIdx.x == 0) {
        __shared__ float red[128];
        float m = (t < 128) ? attn[t] : 0.f;
        if (t < 128) red[t] = Wnm[128 * 128 + t] * m;
        __syncthreads();
        for (int s = 64; s > 0; s >>= 1) { if (t < s) red[t] += red[t + s]; __syncthreads(); }
        if (t == 0) sc[0] = red[0];
        __syncthreads();
        if (t < 128) red[t] = b_nm[t] * m;
        __syncthreads();
        for (int s = 64; s > 0; s >>= 1) { if (t < s) red[t] += red[t + s]; __syncthreads(); }
        if (t == 0) sc[1] = red[0];
        __syncthreads();
        for (int k = 0; k < 16; k++) {
            if (t < 128) red[t] = Wnm[(129 + k) * 128 + t] * m;
            __syncthreads();
            for (int s = 64; s > 0; s >>= 1) { if (t < s) red[t] += red[t + s]; __syncthreads(); }
            if (t == 0) sc[2 + k] = red[0];
            __syncthreads();
        }
    } else if (blockIdx.x <= 33) {
        int idx = (blockIdx.x - 1) * 256 + t;   // 65*128 outputs (row 64 = bias)
        if (idx >= 65 * 128) return;
        int j = idx >> 7, c = idx & 127;
        const float* row = (j < 64) ? &W2[j * 128] : b2;
        float acc = 0.f;
        for (int cp = 0; cp < 128; cp++) acc = fmaf(row[cp], Wnm[cp * 128 + c], acc);
        if (j < 64) Wc[j * 128 + c] = __float2half_rn(acc);
        else bc[c] = acc;
    } else {
        int e = (blockIdx.x - 34) * 256 + t;
        if (e < E) atomicAdd(&counts[dst[e]], 1);
    }
}

__global__ void k_scan_a(const int* counts, int* row_off, int* partials, int n) {
    __shared__ int sd[256];
    int t = threadIdx.x;
    int base = blockIdx.x * 1024 + t * 4;
    int v0 = (base + 0 < n) ? counts[base + 0] : 0;
    int v1 = (base + 1 < n) ? counts[base + 1] : 0;
    int v2 = (base + 2 < n) ? counts[base + 2] : 0;
    int v3 = (base + 3 < n) ? counts[base + 3] : 0;
    int s = v0 + v1 + v2 + v3;
    sd[t] = s; __syncthreads();
    for (int off = 1; off < 256; off <<= 1) {
        int x = (t >= off) ? sd[t - off] : 0;
        __syncthreads();
        sd[t] += x;
        __syncthreads();
    }
    int run = sd[t] - s;
    if (base + 0 < n) row_off[base + 0] = run; run += v0;
    if (base + 1 < n) row_off[base + 1] = run; run += v1;
    if (base + 2 < n) row_off[base + 2] = run; run += v2;
    if (base + 3 < n) row_off[base + 3] = run;
    if (t == 255) partials[blockIdx.x] = sd[255];
}

// ---------- k_Ac: blocks [0, nscan) -> scan_c fixup (+bcur init); rest -> fused k_A
__global__ void __launch_bounds__(256) k_Ac(int* __restrict__ row_off,
                                            const int* __restrict__ partials,
                                            int* __restrict__ bcur,
                                            const float* __restrict__ feat,
                                            const float* __restrict__ W1,
                                            const float* __restrict__ b1,
                                            const float* __restrict__ sc,
                                            const __half* __restrict__ Wc,
                                            const float* __restrict__ bc,
                                            const float* __restrict__ attn,
                                            __half* __restrict__ Ah,
                                            float* __restrict__ a_s,
                                            float* __restrict__ bd,
                                            int n, int E, int ntiles,
                                            int nscan, int gridA) {
    __shared__ __half Wt[128 * 72];       // Wc^T: Wt[c][k], stride 72
    __shared__ float  W1s[16 * 64];
    __shared__ float  b1s[64];
    __shared__ __half t1s[4][16 * 72];
    int t = threadIdx.x;
    if ((int)blockIdx.x < nscan) {
        int i = blockIdx.x * 256 + t;
        if (i < n) {
            int g = i >> 10;
            int acc = 0;
            for (int j = 0; j < g; j++) acc += partials[j];
            int r = row_off[i] + acc;
            row_off[i] = r;
            if ((i & (GSZ - 1)) == 0) bcur[i >> GSZ_SHIFT] = r;
        }
        if (i == 0) row_off[n] = E;
        return;
    }
    int bid = blockIdx.x - nscan;
    for (int idx = t; idx < 64 * 128; idx += 256) {
        int k = idx >> 7, c = idx & 127;
        Wt[c * 72 + k] = Wc[idx];
    }
    for (int idx = t; idx < 1024; idx += 256) W1s[idx] = W1[idx];
    if (t < 64) b1s[t] = b1[t];
    __syncthreads();
    int wave = t >> 6, lane = t & 63;
    int c = lane & 15, q = lane >> 4;
    float attv[8], bcv[8];
#pragma unroll
    for (int ct = 0; ct < 8; ct++) {
        attv[ct] = attn[ct * 16 + c];
        bcv[ct]  = bc[ct * 16 + c];
    }
    float qb[16];
#pragma unroll
    for (int k = 0; k < 16; k++) qb[k] = sc[2 + k];
    __half* myT1 = &t1s[wave][0];
    for (int tile = bid * 4 + wave; tile < ntiles; tile += gridA * 4) {
        int rowbase = tile * 16;
        int rm = min(rowbase + c, n - 1);
        const float4* fr = (const float4*)(feat + (size_t)rm * 16);
        float fv[16];
        *(float4*)&fv[0]  = fr[0];
        *(float4*)&fv[4]  = fr[1];
        *(float4*)&fv[8]  = fr[2];
        *(float4*)&fv[12] = fr[3];
        if (q == 0 && rowbase + c < n) {
            float bacc = 0.f;
#pragma unroll
            for (int k = 0; k < 16; k++) bacc = fmaf(fv[k], qb[k], bacc);
            bd[rowbase + c] = bacc;
        }
        {
            _Float16 tv[16];
#pragma unroll
            for (int jj = 0; jj < 16; jj++) {
                int j = q * 16 + jj;
                float acc = b1s[j];
#pragma unroll
                for (int k = 0; k < 16; k++) acc = fmaf(fv[k], W1s[k * 64 + j], acc);
                tv[jj] = (_Float16)lrelu(acc, 0.1f);
            }
            *(h8*)&myT1[c * 72 + q * 16 + 0] = *(h8*)&tv[0];
            *(h8*)&myT1[c * 72 + q * 16 + 8] = *(h8*)&tv[8];
        }
        h8 af[2];
#pragma unroll
        for (int ks = 0; ks < 2; ks++)
            af[ks] = *(const h8*)&myT1[c * 72 + ks * 32 + q * 8];
        f4 acc[8];
#pragma unroll
        for (int ct = 0; ct < 8; ct++) acc[ct] = (f4)(0.f);
#pragma unroll
        for (int ct = 0; ct < 8; ct++) {
#pragma unroll
            for (int ks = 0; ks < 2; ks++) {
                h8 bf = *(const h8*)&Wt[(ct * 16 + c) * 72 + ks * 32 + q * 8];
                acc[ct] = __builtin_amdgcn_mfma_f32_16x16x32_f16(af[ks], bf, acc[ct], 0, 0, 0);
            }
        }
        int rlim = n - rowbase;
        float s0 = 0.f, s1 = 0.f, s2 = 0.f, s3 = 0.f;
#pragma unroll
        for (int ct = 0; ct < 8; ct++) {
            int col = ct * 16 + c;
            float v0 = acc[ct][0] + bcv[ct];
            float v1 = acc[ct][1] + bcv[ct];
            float v2 = acc[ct][2] + bcv[ct];
            float v3 = acc[ct][3] + bcv[ct];
            if (q * 4 + 0 < rlim) Ah[(size_t)(rowbase + q * 4 + 0) * 128 + col] = __float2half_rn(v0);
            if (q * 4 + 1 < rlim) Ah[(size_t)(rowbase + q * 4 + 1) * 128 + col] = __float2half_rn(v1);
            if (q * 4 + 2 < rlim) Ah[(size_t)(rowbase + q * 4 + 2) * 128 + col] = __float2half_rn(v2);
            if (q * 4 + 3 < rlim) Ah[(size_t)(rowbase + q * 4 + 3) * 128 + col] = __float2half_rn(v3);
            s0 = fmaf(v0, attv[ct], s0);
            s1 = fmaf(v1, attv[ct], s1);
            s2 = fmaf(v2, attv[ct], s2);
            s3 = fmaf(v3, attv[ct], s3);
        }
#pragma unroll
        for (int off = 1; off < 16; off <<= 1) {
            s0 += __shfl_xor(s0, off, 64);
            s1 += __shfl_xor(s1, off, 64);
            s2 += __shfl_xor(s2, off, 64);
            s3 += __shfl_xor(s3, off, 64);
        }
        if (c == 0) {
            if (q * 4 + 0 < rlim) a_s[rowbase + q * 4 + 0] = s0;
            if (q * 4 + 1 < rlim) a_s[rowbase + q * 4 + 1] = s1;
            if (q * 4 + 2 < rlim) a_s[rowbase + q * 4 + 2] = s2;
            if (q * 4 + 3 < rlim) a_s[rowbase + q * 4 + 3] = s3;
        }
    }
}

// ---------- pass 1: binned scatter. Record {src, w, w*bit, dst} into bucket runs.
__global__ void __launch_bounds__(256) k_p1(const int* __restrict__ src,
                                            const int* __restrict__ dst,
                                            const float* __restrict__ bit,
                                            const float* __restrict__ a_s,
                                            const float* __restrict__ bd,
                                            const float* __restrict__ sc,
                                            int* __restrict__ bcur,
                                            float4* __restrict__ tmp,
                                            int E, int NB) {
    __shared__ int hist[NBMAX];
    __shared__ int rbase[NBMAX];
    int t = threadIdx.x;
    int e0 = blockIdx.x * EPB;
    int e1 = min(e0 + EPB, E);
    for (int i = t; i < NB; i += 256) hist[i] = 0;
    __syncthreads();
    for (int e = e0 + t; e < e1; e += 256)
        atomicAdd(&hist[dst[e] >> GSZ_SHIFT], 1);
    __syncthreads();
    for (int i = t; i < NB; i += 256) {
        int c = hist[i];
        rbase[i] = c ? atomicAdd(&bcur[i], c) : 0;
        hist[i] = 0;
    }
    __syncthreads();
    float c1 = sc[0], c0 = sc[1];
    for (int e = e0 + t; e < e1; e += 256) {
        int s = src[e], d = dst[e];
        float bv = bit[e];
        float logit = a_s[s] + c1 * bv + bd[d] + c0;
        float w = __expf(lrelu(logit, 0.2f));
        int b = d >> GSZ_SHIFT;
        int p = rbase[b] + atomicAdd(&hist[b], 1);
        tmp[p] = make_float4(__int_as_float(s), w, w * bv, __int_as_float(d));
    }
}

// ---------- pass 2: per-bucket LDS sort to per-node order; coalesced stream out.
__global__ void __launch_bounds__(256) k_p2(const int* __restrict__ row_off,
                                            const float4* __restrict__ tmp,
                                            float4* __restrict__ recs, int n) {
    __shared__ float4 stg[P2CAP];
    __shared__ int lcur[GSZ + 1];
    int b = blockIdx.x;
    int t = threadIdx.x;
    int v0 = b << GSZ_SHIFT;
    int v1 = min(v0 + GSZ, n);
    int base = row_off[v0];
    int end  = row_off[v1];
    int cnt  = end - base;
    for (int v = v0 + t; v < v1; v += 256) lcur[v - v0] = row_off[v] - base;
    __syncthreads();
    if (cnt <= P2CAP) {
        for (int i = t; i < cnt; i += 256) {
            float4 r = tmp[base + i];
            int d = __float_as_int(r.w);
            int p = atomicAdd(&lcur[d - v0], 1);
            stg[p] = r;
        }
        __syncthreads();
        for (int i = t; i < cnt; i += 256) recs[base + i] = stg[i];
    } else {
        // overflow fallback (statistically unreachable): direct global scatter
        for (int i = t; i < cnt; i += 256) {
            float4 r = tmp[base + i];
            int d = __float_as_int(r.w);
            int p = atomicAdd(&lcur[d - v0], 1);
            recs[base + p] = r;
        }
    }
}

// ---------- per-node aggregate -> h_node fp16; 64 thr, 2 ch/thread ----------
__global__ void __launch_bounds__(64, 4) k_node(const float* __restrict__ feat,
                                                const float* __restrict__ Wnm,
                                                const float* __restrict__ b_nm,
                                                const __half* __restrict__ Ah,
                                                const int* __restrict__ row_off,
                                                const float4* __restrict__ recs,
                                                __half* __restrict__ h_node) {
    int v = blockIdx.x;
    int t = threadIdx.x;
    int rs = row_off[v], re = row_off[v + 1];
    h2f* outp = (h2f*)&h_node[(size_t)v * 128 + 2 * t];
    const float4* fr = (const float4*)(feat + (size_t)v * 16);
    float fv[16];
    *(float4*)&fv[0]  = fr[0];
    *(float4*)&fv[4]  = fr[1];
    *(float4*)&fv[8]  = fr[2];
    *(float4*)&fv[12] = fr[3];
    float Bx = 0.f, By = 0.f;
#pragma unroll
    for (int k = 0; k < 16; k++) {
        float2 wr = *(const float2*)&Wnm[(129 + k) * 128 + 2 * t];
        Bx = fmaf(fv[k], wr.x, Bx);
        By = fmaf(fv[k], wr.y, By);
    }
    if (re == rs) { h2f z; z[0] = (_Float16)0.f; z[1] = (_Float16)0.f; *outp = z; return; }
    float ax = 0.f, ay = 0.f, sw = 0.f, swb = 0.f;
#pragma unroll 8
    for (int p = rs; p < re; ++p) {
        float4 rec = recs[p];
        int sv = __float_as_int(rec.x);
        float2 av = __half22float2(*(const __half2*)&Ah[(size_t)sv * 128 + 2 * t]);
        ax = fmaf(rec.y, av.x, ax);
        ay = fmaf(rec.y, av.y, ay);
        sw += rec.y;
        swb += rec.z;
    }
    float inv = 1.f / sw;
    float2 wb = *(const float2*)&Wnm[128 * 128 + 2 * t];
    float2 bn = *(const float2*)&b_nm[2 * t];
    float hx = fmaf(swb * inv, wb.x, ax * inv) + Bx + bn.x;
    float hy = fmaf(swb * inv, wb.y, ay * inv) + By + bn.y;
    h2f o; o[0] = (_Float16)fmaxf(hx, 0.f); o[1] = (_Float16)fmaxf(hy, 0.f);
    *outp = o;
}

// ---------- out = bo2 + sum_c lrelu(h_node@Wo1+bo1,0.1)[c]*Wo2[c], MFMA ----------
__global__ void __launch_bounds__(256) k_out(const __half* __restrict__ h_node,
                                             const float* __restrict__ Wo1,
                                             const float* __restrict__ bo1,
                                             const float* __restrict__ Wo2,
                                             const float* __restrict__ bo2,
                                             float* __restrict__ out,
                                             int n, int ntiles) {
    __shared__ __half Wt[128 * 136];
    int t = threadIdx.x;
    for (int idx = t; idx < 128 * 128; idx += 256) {
        int k = idx >> 7, c = idx & 127;
        Wt[c * 136 + k] = __float2half_rn(Wo1[idx]);
    }
    __syncthreads();
    int wave = t >> 6, lane = t & 63;
    int c = lane & 15, q = lane >> 4;
    float b1v[8], w2v[8];
#pragma unroll
    for (int ct = 0; ct < 8; ct++) {
        b1v[ct] = bo1[ct * 16 + c];
        w2v[ct] = Wo2[ct * 16 + c];
    }
    float bias2 = bo2[0];
    for (int tile = blockIdx.x * 4 + wave; tile < ntiles; tile += gridDim.x * 4) {
        int rowbase = tile * 16;
        int rm = min(rowbase + c, n - 1);
        h8 af[4];
#pragma unroll
        for (int ks = 0; ks < 4; ks++)
            af[ks] = *(const h8*)&h_node[(size_t)rm * 128 + ks * 32 + q * 8];
        f4 acc[8];
#pragma unroll
        for (int ct = 0; ct < 8; ct++) acc[ct] = (f4)(0.f);
#pragma unroll
        for (int ct = 0; ct < 8; ct++) {
#pragma unroll
            for (int ks = 0; ks < 4; ks++) {
                h8 bf = *(const h8*)&Wt[(ct * 16 + c) * 136 + ks * 32 + q * 8];
                acc[ct] = __builtin_amdgcn_mfma_f32_16x16x32_f16(af[ks], bf, acc[ct], 0, 0, 0);
            }
        }
        int rlim = n - rowbase;
        float s0 = 0.f, s1 = 0.f, s2 = 0.f, s3 = 0.f;
#pragma unroll
        for (int ct = 0; ct < 8; ct++) {
            s0 = fmaf(lrelu(acc[ct][0] + b1v[ct], 0.1f), w2v[ct], s0);
            s1 = fmaf(lrelu(acc[ct][1] + b1v[ct], 0.1f), w2v[ct], s1);
            s2 = fmaf(lrelu(acc[ct][2] + b1v[ct], 0.1f), w2v[ct], s2);
            s3 = fmaf(lrelu(acc[ct][3] + b1v[ct], 0.1f), w2v[ct], s3);
        }
#pragma unroll
        for (int off = 1; off < 16; off <<= 1) {
            s0 += __shfl_xor(s0, off, 64);
            s1 += __shfl_xor(s1, off, 64);
            s2 += __shfl_xor(s2, off, 64);
            s3 += __shfl_xor(s3, off, 64);
        }
        if (c == 0) {
            if (q * 4 + 0 < rlim) out[rowbase + q * 4 + 0] = bias2 + s0;
            if (q * 4 + 1 < rlim) out[rowbase + q * 4 + 1] = bias2 + s1;
            if (q * 4 + 2 < rlim) out[rowbase + q * 4 + 2] = bias2 + s2;
            if (q * 4 + 3 < rlim) out[rowbase + q * 4 + 3] = bias2 + s3;
        }
    }
}

extern "C" void kernel_launch(void* const* d_in, const int* in_sizes, int n_in,
                              void* d_out, int out_size, void* d_ws, size_t ws_size,
                              hipStream_t stream) {
    const float* feat = (const float*)d_in[0];
    const float* bit  = (const float*)d_in[1];
    const int*   src  = (const int*)d_in[2];
    const int*   dst  = (const int*)d_in[3];
    const float* W1   = (const float*)d_in[4];
    const float* b1   = (const float*)d_in[5];
    const float* W2   = (const float*)d_in[6];
    const float* b2   = (const float*)d_in[7];
    const float* Wnm  = (const float*)d_in[8];
    const float* bnm  = (const float*)d_in[9];
    const float* attn = (const float*)d_in[10];
    const float* Wo1  = (const float*)d_in[11];
    const float* bo1  = (const float*)d_in[12];
    const float* Wo2  = (const float*)d_in[13];
    const float* bo2  = (const float*)d_in[14];
    float* out = (float*)d_out;
    int n = in_sizes[0] / 16;
    int E = in_sizes[2];
    int ntiles = (n + 15) / 16;

    char* wsp = (char*)d_ws;
    size_t off = 0;
    auto alloc = [&](size_t bytes) -> void* {
        void* p = wsp + off;
        off = (off + bytes + 255) & ~(size_t)255;
        return p;
    };
    __half* Ah       = (__half*)alloc((size_t)n * 128 * 2);
    __half* h_node   = (__half*)alloc((size_t)n * 128 * 2);
    float*  a_s      = (float*)alloc((size_t)n * 4);
    float*  bd       = (float*)alloc((size_t)n * 4);
    int*    counts   = (int*)alloc((size_t)n * 4);
    int*    row_off  = (int*)alloc((size_t)(n + 1) * 4);
    int*    bcur     = (int*)alloc((size_t)n * 4);
    int*    partials = (int*)alloc(8192);
    float*  sc       = (float*)alloc(256);
    __half* Wc       = (__half*)alloc(64 * 128 * 2);
    float*  bc       = (float*)alloc(128 * 4);
    float4* recs     = (float4*)alloc((size_t)E * 16);
    // tmp (pass-1 bucket-binned records) aliases h_node: dead until k_node,
    // and E*16 == n*256 here. Fall back to a fresh alloc if sizes diverge.
    float4* tmp = ((size_t)E * 16 <= (size_t)n * 256) ? (float4*)h_node
                                                      : (float4*)alloc((size_t)E * 16);

    int nb256 = (n + 255) / 256;
    int eb256 = (E + 255) / 256;
    int nscan = (n + 1023) / 1024;
    int gridA = 1024;
    int NB = (n + GSZ - 1) >> GSZ_SHIFT;
    int gridP1 = (E + EPB - 1) / EPB;

    hipMemsetAsync(counts, 0, (size_t)n * 4, stream);
    k_hp<<<34 + eb256, 256, 0, stream>>>(W2, b2, Wnm, bnm, attn, Wc, bc, sc,
                                         dst, counts, E);
    k_scan_a<<<nscan, 256, 0, stream>>>(counts, row_off, partials, n);
    k_Ac<<<nb256 + gridA, 256, 0, stream>>>(row_off, partials, bcur,
                                            feat, W1, b1, sc, Wc, bc, attn,
                                            Ah, a_s, bd, n, E, ntiles, nb256, gridA);
    k_p1<<<gridP1, 256, 0, stream>>>(src, dst, bit, a_s, bd, sc, bcur, tmp, E, NB);
    k_p2<<<NB, 256, 0, stream>>>(row_off, tmp, recs, n);
    k_node<<<n, 64, 0, stream>>>(feat, Wnm, bnm, Ah, row_off, recs, h_node);
    k_out<<<1024, 256, 0, stream>>>(h_node, Wo1, bo1, Wo2, bo2, out, n, ntiles);
}